// Round 1
// baseline (5729.722 us; speedup 1.0000x reference)
//
#include <hip/hip_runtime.h>

#define H 1024
#define V 32000
#define NSTEP 128
#define NLOGIT_BLK 8000   // V/4 rows, 4 rows per block

// workspace float offsets
#define WS_H0   0         // [2][H] double buffer
#define WS_C0   2048
#define WS_H1   3072      // [2][H] double buffer
#define WS_C1   5120
#define WS_TOK  6144
#define WS_LOGZ 6145
#define WS_PMAX 8192      // [NLOGIT_BLK]
#define WS_PSUM 16384     // [NLOGIT_BLK]
#define WS_PIDX 24576     // [NLOGIT_BLK] (int)

__device__ __forceinline__ float wave_dot(const float4* __restrict__ wrow4,
                                          const float4* __restrict__ v4) {
    int lane = threadIdx.x & 63;
    float acc = 0.f;
#pragma unroll
    for (int k = 0; k < 4; ++k) {
        float4 w = wrow4[lane + 64 * k];
        float4 x = v4[lane + 64 * k];
        acc += w.x * x.x + w.y * x.y + w.z * x.z + w.w * x.w;
    }
#pragma unroll
    for (int off = 32; off > 0; off >>= 1)
        acc += __shfl_down(acc, off, 64);
    return acc;  // valid in lane 0
}

__device__ __forceinline__ float sigmoidf_(float x) {
    return 1.f / (1.f + expf(-x));
}

// ---- setup: ctx = cv0*cv1 ; h = W_up@ctx + b_up ; init h0/c0/h1/c1, tok ----
__global__ __launch_bounds__(256) void k_setup(const float* __restrict__ Wup,
                                               const float* __restrict__ bup,
                                               const float* __restrict__ cv,
                                               const int* __restrict__ y,
                                               float* __restrict__ ws) {
    int r = blockIdx.x;      // 1024 blocks, one row each
    int t = threadIdx.x;
    __shared__ float red[256];
    const float* row = Wup + (size_t)r * H;
    float acc = 0.f;
    for (int j = t; j < H; j += 256) acc += row[j] * (cv[j] * cv[H + j]);
    red[t] = acc;
    __syncthreads();
    for (int s = 128; s > 0; s >>= 1) {
        if (t < s) red[t] += red[t + s];
        __syncthreads();
    }
    if (t == 0) {
        float h = red[0] + bup[r];
        ws[WS_H0 + r] = h;
        ws[WS_C0 + r] = h;
        ws[WS_H1 + r] = h;
        ws[WS_C1 + r] = h;
        if (r == 0) ws[WS_TOK] = (float)y[0];
    }
}

// ---- LSTM layer 0: input is scalar token ----
__global__ __launch_bounds__(256) void k_lstm0(const float* __restrict__ Whh,
                                               const float* __restrict__ Wih_col,
                                               const float* __restrict__ bih,
                                               const float* __restrict__ bhh,
                                               float* __restrict__ ws, int par) {
    __shared__ float4 shv[256];
    __shared__ float gates[4];
    int i = blockIdx.x;   // cell index, 1024 blocks
    int t = threadIdx.x;
    const float* hin = ws + WS_H0 + par * H;
    shv[t] = ((const float4*)hin)[t];
    __syncthreads();
    int w = t >> 6;
    int r = i + (w << 10);
    float d = wave_dot((const float4*)(Whh + (size_t)r * H), shv);
    if ((t & 63) == 0) {
        float tok = ws[WS_TOK];
        gates[w] = d + Wih_col[r] * tok + bih[r] + bhh[r];
    }
    __syncthreads();
    if (t == 0) {
        float ig = sigmoidf_(gates[0]);
        float fg = sigmoidf_(gates[1]);
        float gg = tanhf(gates[2]);
        float og = sigmoidf_(gates[3]);
        float c = fg * ws[WS_C0 + i] + ig * gg;
        ws[WS_C0 + i] = c;
        ws[WS_H0 + (par ^ 1) * H + i] = og * tanhf(c);
    }
}

// ---- LSTM layer 1: input is new h0 ----
__global__ __launch_bounds__(256) void k_lstm1(const float* __restrict__ Wih,
                                               const float* __restrict__ Whh,
                                               const float* __restrict__ bih,
                                               const float* __restrict__ bhh,
                                               float* __restrict__ ws, int par) {
    __shared__ float4 shx[256];
    __shared__ float4 shh[256];
    __shared__ float gates[4];
    int i = blockIdx.x;
    int t = threadIdx.x;
    shx[t] = ((const float4*)(ws + WS_H0 + (par ^ 1) * H))[t];
    shh[t] = ((const float4*)(ws + WS_H1 + par * H))[t];
    __syncthreads();
    int w = t >> 6;
    int r = i + (w << 10);
    float d = wave_dot((const float4*)(Wih + (size_t)r * H), shx) +
              wave_dot((const float4*)(Whh + (size_t)r * H), shh);
    if ((t & 63) == 0) gates[w] = d + bih[r] + bhh[r];
    __syncthreads();
    if (t == 0) {
        float ig = sigmoidf_(gates[0]);
        float fg = sigmoidf_(gates[1]);
        float gg = tanhf(gates[2]);
        float og = sigmoidf_(gates[3]);
        float c = fg * ws[WS_C1 + i] + ig * gg;
        ws[WS_C1 + i] = c;
        ws[WS_H1 + (par ^ 1) * H + i] = og * tanhf(c);
    }
}

// ---- logits: relu(W_out@h1 + b_out) -> out row; per-block softmax partials ----
__global__ __launch_bounds__(256) void k_logits(const float* __restrict__ Wout,
                                                const float* __restrict__ bout,
                                                float* __restrict__ outrow,
                                                float* __restrict__ ws, int par) {
    __shared__ float4 shv[256];
    __shared__ float sval[4];
    int b = blockIdx.x;   // NLOGIT_BLK blocks, 4 rows each
    int t = threadIdx.x;
    shv[t] = ((const float4*)(ws + WS_H1 + (par ^ 1) * H))[t];
    __syncthreads();
    int w = t >> 6;
    int r = b * 4 + w;
    float d = wave_dot((const float4*)(Wout + (size_t)r * H), shv);
    if ((t & 63) == 0) {
        float v = d + bout[r];
        v = v > 0.f ? v : 0.f;   // relu
        outrow[r] = v;
        sval[w] = v;
    }
    __syncthreads();
    if (t == 0) {
        float m = sval[0];
        int mi = 0;
#pragma unroll
        for (int k = 1; k < 4; ++k)
            if (sval[k] > m) { m = sval[k]; mi = k; }
        float s = 0.f;
#pragma unroll
        for (int k = 0; k < 4; ++k) s += expf(sval[k] - m);
        ws[WS_PMAX + b] = m;
        ws[WS_PSUM + b] = s;
        ((int*)ws)[WS_PIDX + b] = b * 4 + mi;
    }
}

// ---- merge partials -> logZ, next token ----
__global__ __launch_bounds__(1024) void k_reduce(float* __restrict__ ws) {
    __shared__ float sm[1024];
    __shared__ float ssum[1024];
    __shared__ int si[1024];
    int t = threadIdx.x;
    float m = -1e30f, s = 0.f;
    int idx = 0x7fffffff;
    for (int b = t; b < NLOGIT_BLK; b += 1024) {
        float bm = ws[WS_PMAX + b];
        float bs = ws[WS_PSUM + b];
        int bi = ((int*)ws)[WS_PIDX + b];
        if (bm > m) {
            s = s * expf(m - bm) + bs;
            m = bm;
            idx = bi;
        } else if (bm == m) {
            s += bs;
            if (bi < idx) idx = bi;
        } else {
            s += bs * expf(bm - m);
        }
    }
    sm[t] = m; ssum[t] = s; si[t] = idx;
    __syncthreads();
    for (int o = 512; o > 0; o >>= 1) {
        if (t < o) {
            float m2 = sm[t + o], s2 = ssum[t + o];
            int i2 = si[t + o];
            if (m2 > sm[t]) {
                ssum[t] = ssum[t] * expf(sm[t] - m2) + s2;
                sm[t] = m2;
                si[t] = i2;
            } else if (m2 == sm[t]) {
                ssum[t] += s2;
                if (i2 < si[t]) si[t] = i2;
            } else {
                ssum[t] += s2 * expf(m2 - sm[t]);
            }
        }
        __syncthreads();
    }
    if (t == 0) {
        ws[WS_LOGZ] = sm[0] + logf(ssum[0]);
        ws[WS_TOK] = (float)si[0];
    }
}

// ---- normalize row: out -= logZ ----
__global__ __launch_bounds__(256) void k_norm(float* __restrict__ outrow,
                                              const float* __restrict__ ws) {
    int i = blockIdx.x * 256 + threadIdx.x;
    float lz = ws[WS_LOGZ];
    if (i < V) outrow[i] -= lz;
}

extern "C" void kernel_launch(void* const* d_in, const int* in_sizes, int n_in,
                              void* d_out, int out_size, void* d_ws, size_t ws_size,
                              hipStream_t stream) {
    const int*   y    = (const int*)d_in[0];
    const float* cv   = (const float*)d_in[1];
    // d_in[2] = stride (128), compile-time constant here
    const float* Wup  = (const float*)d_in[3];
    const float* bup  = (const float*)d_in[4];
    const float* Wih0 = (const float*)d_in[5];   // [4096,1] -> column
    const float* Whh0 = (const float*)d_in[6];
    const float* bih0 = (const float*)d_in[7];
    const float* bhh0 = (const float*)d_in[8];
    const float* Wih1 = (const float*)d_in[9];
    const float* Whh1 = (const float*)d_in[10];
    const float* bih1 = (const float*)d_in[11];
    const float* bhh1 = (const float*)d_in[12];
    const float* Wout = (const float*)d_in[13];
    const float* bout = (const float*)d_in[14];
    float* out = (float*)d_out;
    float* ws  = (float*)d_ws;

    k_setup<<<1024, 256, 0, stream>>>(Wup, bup, cv, y, ws);
    for (int t = 0; t < NSTEP; ++t) {
        int par = t & 1;
        k_lstm0<<<1024, 256, 0, stream>>>(Whh0, Wih0, bih0, bhh0, ws, par);
        k_lstm1<<<1024, 256, 0, stream>>>(Wih1, Whh1, bih1, bhh1, ws, par);
        k_logits<<<NLOGIT_BLK, 256, 0, stream>>>(Wout, bout, out + (size_t)t * V, ws, par);
        k_reduce<<<1, 1024, 0, stream>>>(ws);
        k_norm<<<125, 256, 0, stream>>>(out + (size_t)t * V, ws);
    }
}